// Round 10
// baseline (611.705 us; speedup 1.0000x reference)
//
#include <hip/hip_runtime.h>
#include <math.h>

// Problem constants (fixed by setup_inputs)
#define QTOT   8192
#define LNUM   4
#define PNUM   4
#define NHEAD  8
#define DHEAD  32
#define HMAX   128
#define NV_PER_B 21760           // 128^2 + 64^2 + 32^2 + 16^2
#define MROWS  (2 * NV_PER_B)    // 43520 valid value rows
#define QPERB  4096              // batch_offsets = [0, 4096]

// grouped-GEMM grid split
#define G1_MT  (MROWS / 128)     // 340 m-tiles for vproj GEMM
#define G1_BLKS (G1_MT * 2)      // 680 (N=256 -> 2 n-tiles)
#define G2_BLKS (128 * 3)        // 384 (M=8192/64, N=384 -> 3 n-tiles)

// ===== MEASUREMENT ROUND: idempotent in-kernel repeats to lift each kernel
// above the ~80us fill floor so top-5 shows per-kernel dur + counters.
// True per-kernel time = dur / REP (upper bound; reps 2+ are L3-warm).
#define REP_G12  4
#define REP_SAMP 4
#define REP_O    8

typedef __attribute__((ext_vector_type(8))) short bf16x8;
typedef __attribute__((ext_vector_type(4))) float f32x4;

static __device__ __forceinline__ ushort bf16_hi(float f) {
    return (ushort)(__builtin_bit_cast(unsigned int, f) >> 16);
}
static __device__ __forceinline__ ushort bf16_lo(float f, ushort hi) {
    float hf = __builtin_bit_cast(float, ((unsigned int)hi) << 16);
    return (ushort)(__builtin_bit_cast(unsigned int, f - hf) >> 16);
}
static __device__ __forceinline__ ushort bf16_rne(float f) {
    unsigned u = __builtin_bit_cast(unsigned int, f);
    unsigned rr = (u + 0x7FFFu + ((u >> 16) & 1u)) >> 16;
    return (ushort)rr;
}

// ---------------------------------------------------------------------------
// Split-bf16 MFMA NT GEMM body (unchanged from R9). smem caller-provided.
//   mode1 <1,128,1,1>: 32.5 KB   mode2 <0,64,3,0>: 48 KB   out <0,64,1,0>: 24 KB
// ---------------------------------------------------------------------------
template<int GATHER, int BM, int NPROD, int OUTBF16>
__device__ __forceinline__
void gemm_body(const float* __restrict__ A,
               const float* __restrict__ B1,
               const float* __restrict__ B2,
               const float* __restrict__ bias1,
               const float* __restrict__ bias2,
               void* __restrict__ Out,
               int nsplit, int ldo, int bx, int by, char* smem)
{
    constexpr int MI  = BM / 32;
    constexpr int AIT = BM * 8 / 256;
    constexpr int PL  = (NPROD > 1) ? 2 : 1;
    ushort* sAp = (ushort*)smem;
    ushort* sBp = sAp + 2 * PL * BM * 32;
    int* rowBase = (int*)(sBp + 2 * PL * 128 * 32);

    const int tid = threadIdx.x;
    const int m0 = bx * BM;
    const int n0 = by * 128;

    if (GATHER) {
        for (int s = tid; s < BM; s += 256) {
            int r = m0 + s;
            int b = (r >= NV_PER_B) ? 1 : 0;
            int rp = r - b * NV_PER_B;
            int l, y, x;
            if (rp < 16384)      { l = 0; y = rp >> 7; x = rp & 127; }
            else if (rp < 20480) { int rr = rp - 16384; l = 1; y = rr >> 6; x = rr & 63; }
            else if (rp < 21504) { int rr = rp - 20480; l = 2; y = rr >> 5; x = rr & 31; }
            else                 { int rr = rp - 21504; l = 3; y = rr >> 4; x = rr & 15; }
            rowBase[s] = (((((b << 7) | y) << 7) | x) * 4 + l) << 8;
        }
        __syncthreads();
    }

    float4 pa[AIT], pb[4];

    auto loadA = [&](int kt) {
        #pragma unroll
        for (int i = 0; i < AIT; ++i) {
            int s = tid + i * 256;
            int r = s >> 3, c4 = s & 7;
            const float* src = GATHER
                ? A + rowBase[r] + kt * 32 + c4 * 4
                : A + (size_t)(m0 + r) * 256 + kt * 32 + c4 * 4;
            pa[i] = *(const float4*)src;
        }
        #pragma unroll
        for (int i = 0; i < 4; ++i) {
            int s = tid + i * 256;
            int r = s >> 3, c4 = s & 7;
            int bn = n0 + r;
            const float* src = ((bn < nsplit) ? B1 + (size_t)bn * 256
                                              : B2 + (size_t)(bn - nsplit) * 256)
                               + kt * 32 + c4 * 4;
            pb[i] = *(const float4*)src;
        }
    };

    auto writeLDS = [&](int buf) {
        #pragma unroll
        for (int i = 0; i < AIT; ++i) {
            int s = tid + i * 256;
            int r = s >> 3, c4 = s & 7;
            float4 v = pa[i];
            ushort4 hi;
            hi.x = bf16_hi(v.x); hi.y = bf16_hi(v.y);
            hi.z = bf16_hi(v.z); hi.w = bf16_hi(v.w);
            int idx = r * 32 + ((((c4 >> 1) ^ (r & 3)) << 3) | ((c4 & 1) << 2));
            *(ushort4*)&sAp[(buf * PL + 0) * BM * 32 + idx] = hi;
            if (NPROD > 1) {
                ushort4 lo;
                lo.x = bf16_lo(v.x, hi.x); lo.y = bf16_lo(v.y, hi.y);
                lo.z = bf16_lo(v.z, hi.z); lo.w = bf16_lo(v.w, hi.w);
                *(ushort4*)&sAp[(buf * PL + PL - 1) * BM * 32 + idx] = lo;
            }
        }
        #pragma unroll
        for (int i = 0; i < 4; ++i) {
            int s = tid + i * 256;
            int r = s >> 3, c4 = s & 7;
            float4 v = pb[i];
            ushort4 hi;
            hi.x = bf16_hi(v.x); hi.y = bf16_hi(v.y);
            hi.z = bf16_hi(v.z); hi.w = bf16_hi(v.w);
            int idx = r * 32 + ((((c4 >> 1) ^ (r & 3)) << 3) | ((c4 & 1) << 2));
            *(ushort4*)&sBp[(buf * PL + 0) * 128 * 32 + idx] = hi;
            if (NPROD > 1) {
                ushort4 lo;
                lo.x = bf16_lo(v.x, hi.x); lo.y = bf16_lo(v.y, hi.y);
                lo.z = bf16_lo(v.z, hi.z); lo.w = bf16_lo(v.w, hi.w);
                *(ushort4*)&sBp[(buf * PL + PL - 1) * 128 * 32 + idx] = lo;
            }
        }
    };

    const int lane = tid & 63;
    const int wid  = tid >> 6;
    const int wrow = (wid >> 1) * (BM / 2);
    const int wcol = (wid & 1) * 64;
    const int fr   = lane & 15;
    const int ks   = lane >> 4;

    f32x4 acc[MI][4] = {};

    loadA(0);
    writeLDS(0);

    for (int kt = 0; kt < 8; ++kt) {
        __syncthreads();
        if (kt < 7) loadA(kt + 1);

        const int buf = kt & 1;
        bf16x8 ah[MI], al[MI], bh[4], bl[4];
        #pragma unroll
        for (int mi = 0; mi < MI; ++mi) {
            int row = wrow + mi * 16 + fr;
            int idx = row * 32 + ((ks ^ (row & 3)) << 3);
            ah[mi] = *(const bf16x8*)&sAp[(buf * PL + 0) * BM * 32 + idx];
            if (NPROD > 1) al[mi] = *(const bf16x8*)&sAp[(buf * PL + PL - 1) * BM * 32 + idx];
        }
        #pragma unroll
        for (int ni = 0; ni < 4; ++ni) {
            int row = wcol + ni * 16 + fr;
            int idx = row * 32 + ((ks ^ (row & 3)) << 3);
            bh[ni] = *(const bf16x8*)&sBp[(buf * PL + 0) * 128 * 32 + idx];
            if (NPROD > 1) bl[ni] = *(const bf16x8*)&sBp[(buf * PL + PL - 1) * 128 * 32 + idx];
        }
        #pragma unroll
        for (int mi = 0; mi < MI; ++mi)
            #pragma unroll
            for (int ni = 0; ni < 4; ++ni) {
                acc[mi][ni] = __builtin_amdgcn_mfma_f32_16x16x32_bf16(ah[mi], bh[ni], acc[mi][ni], 0, 0, 0);
                if (NPROD > 1) {
                    acc[mi][ni] = __builtin_amdgcn_mfma_f32_16x16x32_bf16(ah[mi], bl[ni], acc[mi][ni], 0, 0, 0);
                    acc[mi][ni] = __builtin_amdgcn_mfma_f32_16x16x32_bf16(al[mi], bh[ni], acc[mi][ni], 0, 0, 0);
                }
            }

        if (kt < 7) writeLDS((kt + 1) & 1);
    }

    #pragma unroll
    for (int mi = 0; mi < MI; ++mi)
        #pragma unroll
        for (int ni = 0; ni < 4; ++ni) {
            int col = n0 + wcol + ni * 16 + fr;
            float bs = (col < nsplit) ? bias1[col] : bias2[col - nsplit];
            int rbase = m0 + wrow + mi * 16 + ks * 4;
            #pragma unroll
            for (int rr = 0; rr < 4; ++rr) {
                float val = acc[mi][ni][rr] + bs;
                if (OUTBF16)
                    ((ushort*)Out)[(size_t)(rbase + rr) * ldo + col] = bf16_rne(val);
                else
                    ((float*)Out)[(size_t)(rbase + rr) * ldo + col] = val;
            }
        }
}

// ---------------------------------------------------------------------------
// Grouped GEMM1+GEMM2 (R9 structure), repeated REP_G12x for attribution.
// ---------------------------------------------------------------------------
__global__ __launch_bounds__(256)
void fused_g12(const float* __restrict__ values,
               const float* __restrict__ W_v,  const float* __restrict__ b_v,
               const float* __restrict__ query,
               const float* __restrict__ W_so, const float* __restrict__ W_aw,
               const float* __restrict__ b_so, const float* __restrict__ b_aw,
               ushort* __restrict__ vproj, float* __restrict__ qbuf)
{
    extern __shared__ char smem[];
    const int f = blockIdx.x;
    for (int rep = 0; rep < REP_G12; ++rep) {
        if (rep) __syncthreads();   // protect LDS reuse across reps
        if (f < G1_BLKS) {
            gemm_body<1, 128, 1, 1>(values, W_v, W_v, b_v, b_v, vproj,
                                    256, 256, f % G1_MT, f / G1_MT, smem);
        } else {
            const int g = f - G1_BLKS;
            gemm_body<0, 64, 3, 0>(query, W_so, W_aw, b_so, b_aw, qbuf,
                                   256, 384, g % 128, g / 128, smem);
        }
    }
}

// output projection, repeated REP_Ox
__global__ __launch_bounds__(256)
void gemm_o(const float* __restrict__ mid,
            const float* __restrict__ W_o, const float* __restrict__ b_o,
            float* __restrict__ out)
{
    extern __shared__ char smem[];
    for (int rep = 0; rep < REP_O; ++rep) {
        if (rep) __syncthreads();
        gemm_body<0, 64, 1, 0>(mid, W_o, W_o, b_o, b_o, out,
                               256, 256, blockIdx.x, blockIdx.y, smem);
    }
}

// ---------------------------------------------------------------------------
// Sampling (R9 structure), repeated REP_SAMPx. Each rep fully recomputes
// s_rw from qbuf/ref (phase 1), so the in-place aw-fold stays idempotent.
// ---------------------------------------------------------------------------
__global__ __launch_bounds__(256)
void sample1(const ushort* __restrict__ vproj,  // [MROWS][256] bf16
             const float* __restrict__ qbuf,    // [Q][384]
             const float* __restrict__ ref,     // [Q][2]
             float* __restrict__ mid)           // [Q][256]
{
    __shared__ int2  s_rw[128][4];
    __shared__ float s_logit[16][8];
    __shared__ float s_aw[16][8];

    const int tid = threadIdx.x;
    const int q = blockIdx.x;
    const int b = (q >= QPERB) ? 1 : 0;

    for (int rep = 0; rep < REP_SAMP; ++rep) {
    if (rep) __syncthreads();

    if (tid < 128) {
        const int c  = tid;
        const int lp = c >> 3;
        const int l  = lp >> 2;
        const float2 off = *(const float2*)&qbuf[(size_t)q * 384 + c * 2];
        float rx = fminf(fmaxf(ref[q * 2 + 0], 0.f), 1.f);
        float ry = fminf(fmaxf(ref[q * 2 + 1], 0.f), 1.f);
        const float eps = 1e-5f;
        const float isx = logf(fmaxf(rx, eps) / fmaxf(1.f - rx, eps));
        const float isy = logf(fmaxf(ry, eps) / fmaxf(1.f - ry, eps));
        const float locx = 1.f / (1.f + expf(-(isx + off.x)));
        const float locy = 1.f / (1.f + expf(-(isy + off.y)));
        const int Wl = HMAX >> l, Hl = HMAX >> l;
        const float x = locx * (float)Wl - 0.5f;
        const float y = locy * (float)Hl - 0.5f;
        const float x0f = floorf(x), y0f = floorf(y);
        const float wx1 = x - x0f, wx0 = 1.f - wx1;
        const float wy1 = y - y0f, wy0 = 1.f - wy1;
        const int x0 = (int)x0f, y0 = (int)y0f;
        const int lo = (l == 0) ? 0 : (l == 1) ? 16384 : (l == 2) ? 20480 : 21504;
        const int base = b * NV_PER_B + lo;
        const int   xs[2] = {x0, x0 + 1};
        const int   ys[2] = {y0, y0 + 1};
        const float wxs[2] = {wx0, wx1};
        const float wys[2] = {wy0, wy1};
        #pragma unroll
        for (int cy = 0; cy < 2; ++cy)
            #pragma unroll
            for (int cx = 0; cx < 2; ++cx) {
                const int xi = xs[cx], yi = ys[cy];
                const bool valid = (xi >= 0) & (xi < Wl) & (yi >= 0) & (yi < Hl);
                const int idx = cy * 2 + cx;
                s_rw[c][idx].x = valid ? (base + yi * Wl + xi) : 0;
                s_rw[c][idx].y = __float_as_int(valid ? (wys[cy] * wxs[cx]) : 0.f);
            }
        s_logit[lp][c & 7] = qbuf[(size_t)q * 384 + 256 + c];
    }
    __syncthreads();

    if (tid < 8) {
        const int h = tid;
        float m = -INFINITY;
        #pragma unroll
        for (int j = 0; j < 16; ++j) m = fmaxf(m, s_logit[j][h]);
        float s = 0.f;
        #pragma unroll
        for (int j = 0; j < 16; ++j) s += expf(s_logit[j][h] - m);
        const float inv = 1.f / s;
        #pragma unroll
        for (int j = 0; j < 16; ++j)
            s_aw[j][h] = expf(s_logit[j][h] - m) * inv;
    }
    __syncthreads();

    #pragma unroll
    for (int t2 = tid; t2 < 512; t2 += 256) {
        const int c = t2 >> 2, j = t2 & 3;
        const float aw = s_aw[c >> 3][c & 7];
        s_rw[c][j].y = __float_as_int(__int_as_float(s_rw[c][j].y) * aw);
    }
    __syncthreads();

    const int h  = tid >> 5;
    const int l5 = tid & 31;
    const int ds = l5 & 3;
    const int rt = l5 >> 2;
    const int j  = rt & 3;
    const int rtH = rt >> 2;

    float a0 = 0.f, a1 = 0.f, a2 = 0.f, a3 = 0.f;
    float a4 = 0.f, a5 = 0.f, a6 = 0.f, a7 = 0.f;
    #pragma unroll
    for (int it = 0; it < 8; ++it) {
        const int lp = 2 * it + rtH;
        const int c = lp * 8 + h;
        const int2 rw = s_rw[c][j];
        const float w = __int_as_float(rw.y);
        const uint4 u = *(const uint4*)&vproj[(size_t)rw.x * 256 + h * 32 + ds * 8];
        a0 = fmaf(w, __builtin_bit_cast(float, u.x << 16), a0);
        a1 = fmaf(w, __builtin_bit_cast(float, u.x & 0xFFFF0000u), a1);
        a2 = fmaf(w, __builtin_bit_cast(float, u.y << 16), a2);
        a3 = fmaf(w, __builtin_bit_cast(float, u.y & 0xFFFF0000u), a3);
        a4 = fmaf(w, __builtin_bit_cast(float, u.z << 16), a4);
        a5 = fmaf(w, __builtin_bit_cast(float, u.z & 0xFFFF0000u), a5);
        a6 = fmaf(w, __builtin_bit_cast(float, u.w << 16), a6);
        a7 = fmaf(w, __builtin_bit_cast(float, u.w & 0xFFFF0000u), a7);
    }
    #pragma unroll
    for (int m = 4; m <= 16; m <<= 1) {
        a0 += __shfl_xor(a0, m); a1 += __shfl_xor(a1, m);
        a2 += __shfl_xor(a2, m); a3 += __shfl_xor(a3, m);
        a4 += __shfl_xor(a4, m); a5 += __shfl_xor(a5, m);
        a6 += __shfl_xor(a6, m); a7 += __shfl_xor(a7, m);
    }
    if (rt == 0) {
        float* dst = &mid[(size_t)q * 256 + h * 32 + ds * 8];
        float4 o0 = {a0, a1, a2, a3};
        float4 o1 = {a4, a5, a6, a7};
        *(float4*)dst = o0;
        *(float4*)(dst + 4) = o1;
    }
    } // rep
}

// ---------------------------------------------------------------------------
extern "C" void kernel_launch(void* const* d_in, const int* in_sizes, int n_in,
                              void* d_out, int out_size, void* d_ws, size_t ws_size,
                              hipStream_t stream)
{
    const float* query  = (const float*)d_in[0];
    const float* ref    = (const float*)d_in[1];
    const float* values = (const float*)d_in[2];
    const float* W_so   = (const float*)d_in[3];
    const float* b_so   = (const float*)d_in[4];
    const float* W_aw   = (const float*)d_in[5];
    const float* b_aw   = (const float*)d_in[6];
    const float* W_v    = (const float*)d_in[7];
    const float* b_v    = (const float*)d_in[8];
    const float* W_o    = (const float*)d_in[9];
    const float* b_o    = (const float*)d_in[10];
    float* out = (float*)d_out;

    ushort* vproj = (ushort*)d_ws;                     // [43520][256] bf16
    float* qbuf  = (float*)d_ws + ((size_t)MROWS * 256 * 2) / 4;  // [8192][384] f32
    float* mid   = qbuf + (size_t)QTOT * 384;          // [8192][256] f32

    const int smem_bytes = 48 * 1024 + 1024;

    dim3 blk(256);
    fused_g12<<<dim3(G1_BLKS + G2_BLKS), blk, smem_bytes, stream>>>(
        values, W_v, b_v, query, W_so, W_aw, b_so, b_aw, vproj, qbuf);
    sample1<<<dim3(QTOT), blk, 0, stream>>>(vproj, qbuf, ref, mid);
    gemm_o<<<dim3(QTOT / 64, 2), blk, smem_bytes, stream>>>(mid, W_o, b_o, out);
}

// Round 11
// 317.104 us; speedup vs baseline: 1.9290x; 1.9290x over previous
//
#include <hip/hip_runtime.h>
#include <math.h>

// Problem constants (fixed by setup_inputs)
#define QTOT   8192
#define HMAX   128
#define NV_PER_B 21760           // 128^2 + 64^2 + 32^2 + 16^2
#define MROWS  (2 * NV_PER_B)    // 43520 valid value rows
#define QPERB  4096              // batch_offsets = [0, 4096]

// direct-GEMM grid split (block = 128 rows x 64 cols, 4 waves of 32x64)
#define G1_BLKS (340 * 4)        // vproj: 43520/128 m-tiles x 256/64 col-groups
#define G2_BLKS (64 * 6)         // qproj: 8192/128 x 384/64

typedef __attribute__((ext_vector_type(8))) short bf16x8;
typedef __attribute__((ext_vector_type(4))) float f32x4;

static __device__ __forceinline__ ushort bf16_hi(float f) {
    return (ushort)(__builtin_bit_cast(unsigned int, f) >> 16);
}
static __device__ __forceinline__ ushort bf16_lo(float f, ushort hi) {
    float hf = __builtin_bit_cast(float, ((unsigned int)hi) << 16);
    return (ushort)(__builtin_bit_cast(unsigned int, f - hf) >> 16);
}
static __device__ __forceinline__ ushort bf16_rne(float f) {
    unsigned u = __builtin_bit_cast(unsigned int, f);
    unsigned rr = (u + 0x7FFFu + ((u >> 16) & 1u)) >> 16;
    return (ushort)rr;
}
static __device__ __forceinline__ bf16x8 cvt_hi8(float4 v0, float4 v1) {
    bf16x8 r;
    r[0] = (short)bf16_hi(v0.x); r[1] = (short)bf16_hi(v0.y);
    r[2] = (short)bf16_hi(v0.z); r[3] = (short)bf16_hi(v0.w);
    r[4] = (short)bf16_hi(v1.x); r[5] = (short)bf16_hi(v1.y);
    r[6] = (short)bf16_hi(v1.z); r[7] = (short)bf16_hi(v1.w);
    return r;
}
static __device__ __forceinline__ bf16x8 cvt_lo8(float4 v0, float4 v1, bf16x8 h) {
    bf16x8 r;
    r[0] = (short)bf16_lo(v0.x, (ushort)h[0]); r[1] = (short)bf16_lo(v0.y, (ushort)h[1]);
    r[2] = (short)bf16_lo(v0.z, (ushort)h[2]); r[3] = (short)bf16_lo(v0.w, (ushort)h[3]);
    r[4] = (short)bf16_lo(v1.x, (ushort)h[4]); r[5] = (short)bf16_lo(v1.y, (ushort)h[5]);
    r[6] = (short)bf16_lo(v1.z, (ushort)h[6]); r[7] = (short)bf16_lo(v1.w, (ushort)h[7]);
    return r;
}

// compact valid-row id -> pointer into sparse [B,HMAX,HMAX,L,C] values tensor
static __device__ __forceinline__ const float* gather_row_ptr(const float* A, int r) {
    int b = (r >= NV_PER_B) ? 1 : 0;
    int rp = r - b * NV_PER_B;
    int l, y, x;
    if (rp < 16384)      { l = 0; y = rp >> 7; x = rp & 127; }
    else if (rp < 20480) { int rr = rp - 16384; l = 1; y = rr >> 6; x = rr & 63; }
    else if (rp < 21504) { int rr = rp - 20480; l = 2; y = rr >> 5; x = rr & 31; }
    else                 { int rr = rp - 21504; l = 3; y = rr >> 4; x = rr & 15; }
    return A + ((size_t)((((((b << 7) | y) << 7) | x) * 4) + l) << 8);
}

// ---------------------------------------------------------------------------
// Direct-fragment split-bf16 MFMA NT GEMM: Out[M][ldo] = A[M][256]*B[N][256]^T
// + bias. NO LDS, NO barriers: each lane loads its MFMA fragments straight
// from global (lane l holds X[row=l&15][k=(l>>4)*8..+7], the layout verified
// in R5-R9). Wave = 32 rows x 64 cols (MI=2, NI=4), block = 4 waves = 128x64.
// B rows come from L2 (weights <= 384 KB); K=256 -> 8 kt steps, fully
// unrolled, compiler free to hoist loads across MFMAs (no sync points).
// NPROD=3: ahi*bhi + ahi*blo + alo*bhi ; NPROD=1: plain bf16 (hi only).
// ---------------------------------------------------------------------------
template<int GATHER, int NPROD, int OUTBF16>
__device__ __forceinline__
void gemm_direct(const float* __restrict__ A,
                 const float* __restrict__ B1,
                 const float* __restrict__ B2,
                 const float* __restrict__ bias1,
                 const float* __restrict__ bias2,
                 void* __restrict__ Out,
                 int nsplit, int ldo, int bx, int by)
{
    const int tid  = threadIdx.x;
    const int lane = tid & 63;
    const int wid  = tid >> 6;
    const int fr   = lane & 15;     // fragment row (A-row / B-col)
    const int ks   = lane >> 4;     // k-seg: 8 consecutive k per seg
    const int m0   = bx * 128 + wid * 32;
    const int n0   = by * 64;

    const float* Arow0 = GATHER ? gather_row_ptr(A, m0 + fr)
                                : A + (size_t)(m0 + fr) * 256;
    const float* Arow1 = GATHER ? gather_row_ptr(A, m0 + 16 + fr)
                                : A + (size_t)(m0 + 16 + fr) * 256;
    const float* Brow[4];
    #pragma unroll
    for (int ni = 0; ni < 4; ++ni) {
        const int col = n0 + ni * 16 + fr;
        Brow[ni] = (col < nsplit) ? B1 + (size_t)col * 256
                                  : B2 + (size_t)(col - nsplit) * 256;
    }

    f32x4 acc[2][4] = {};

    #pragma unroll
    for (int kt = 0; kt < 8; ++kt) {
        const int ko = kt * 32 + ks * 8;
        const float4 a00 = *(const float4*)(Arow0 + ko);
        const float4 a01 = *(const float4*)(Arow0 + ko + 4);
        const float4 a10 = *(const float4*)(Arow1 + ko);
        const float4 a11 = *(const float4*)(Arow1 + ko + 4);
        const bf16x8 ah0 = cvt_hi8(a00, a01);
        const bf16x8 ah1 = cvt_hi8(a10, a11);
        bf16x8 al0, al1;
        if (NPROD > 1) { al0 = cvt_lo8(a00, a01, ah0); al1 = cvt_lo8(a10, a11, ah1); }
        #pragma unroll
        for (int ni = 0; ni < 4; ++ni) {
            const float4 b0 = *(const float4*)(Brow[ni] + ko);
            const float4 b1 = *(const float4*)(Brow[ni] + ko + 4);
            const bf16x8 bh = cvt_hi8(b0, b1);
            acc[0][ni] = __builtin_amdgcn_mfma_f32_16x16x32_bf16(ah0, bh, acc[0][ni], 0, 0, 0);
            acc[1][ni] = __builtin_amdgcn_mfma_f32_16x16x32_bf16(ah1, bh, acc[1][ni], 0, 0, 0);
            if (NPROD > 1) {
                const bf16x8 bl = cvt_lo8(b0, b1, bh);
                acc[0][ni] = __builtin_amdgcn_mfma_f32_16x16x32_bf16(ah0, bl, acc[0][ni], 0, 0, 0);
                acc[0][ni] = __builtin_amdgcn_mfma_f32_16x16x32_bf16(al0, bh, acc[0][ni], 0, 0, 0);
                acc[1][ni] = __builtin_amdgcn_mfma_f32_16x16x32_bf16(ah1, bl, acc[1][ni], 0, 0, 0);
                acc[1][ni] = __builtin_amdgcn_mfma_f32_16x16x32_bf16(al1, bh, acc[1][ni], 0, 0, 0);
            }
        }
    }

    // epilogue: D[row=(lane>>4)*4+rr][col=lane&15] per 16x16 frag
    #pragma unroll
    for (int mi = 0; mi < 2; ++mi)
        #pragma unroll
        for (int ni = 0; ni < 4; ++ni) {
            const int col = n0 + ni * 16 + fr;
            const float bs = (col < nsplit) ? bias1[col] : bias2[col - nsplit];
            const int rbase = m0 + mi * 16 + ks * 4;
            #pragma unroll
            for (int rr = 0; rr < 4; ++rr) {
                const float val = acc[mi][ni][rr] + bs;
                if (OUTBF16)
                    ((ushort*)Out)[(size_t)(rbase + rr) * ldo + col] = bf16_rne(val);
                else
                    ((float*)Out)[(size_t)(rbase + rr) * ldo + col] = val;
            }
        }
}

// ---------------------------------------------------------------------------
// Grouped GEMM1 (vproj) + GEMM2 (qbuf): independent, one grid fills machine.
// ---------------------------------------------------------------------------
__global__ __launch_bounds__(256)
void fused_g12(const float* __restrict__ values,
               const float* __restrict__ W_v,  const float* __restrict__ b_v,
               const float* __restrict__ query,
               const float* __restrict__ W_so, const float* __restrict__ W_aw,
               const float* __restrict__ b_so, const float* __restrict__ b_aw,
               ushort* __restrict__ vproj, float* __restrict__ qbuf)
{
    const int f = blockIdx.x;
    if (f < G1_BLKS) {
        gemm_direct<1, 1, 1>(values, W_v, W_v, b_v, b_v, vproj,
                             256, 256, f % 340, f / 340);
    } else {
        const int g = f - G1_BLKS;
        gemm_direct<0, 3, 0>(query, W_so, W_aw, b_so, b_aw, qbuf,
                             256, 384, g % 64, g / 64);
    }
}

// output projection
__global__ __launch_bounds__(256)
void gemm_o(const float* __restrict__ mid,
            const float* __restrict__ W_o, const float* __restrict__ b_o,
            float* __restrict__ out)
{
    gemm_direct<0, 1, 0>(mid, W_o, W_o, b_o, b_o, out,
                         256, 256, blockIdx.x, blockIdx.y);
}

// ---------------------------------------------------------------------------
// Sampling (R9 structure): one query per block, 256 threads.
// ---------------------------------------------------------------------------
__global__ __launch_bounds__(256)
void sample1(const ushort* __restrict__ vproj,  // [MROWS][256] bf16
             const float* __restrict__ qbuf,    // [Q][384]: 256 offs | 128 logits
             const float* __restrict__ ref,     // [Q][2]
             float* __restrict__ mid)           // [Q][256]
{
    __shared__ int2  s_rw[128][4];
    __shared__ float s_logit[16][8];
    __shared__ float s_aw[16][8];

    const int tid = threadIdx.x;
    const int q = blockIdx.x;
    const int b = (q >= QPERB) ? 1 : 0;

    if (tid < 128) {
        const int c  = tid;
        const int lp = c >> 3;
        const int l  = lp >> 2;
        const float2 off = *(const float2*)&qbuf[(size_t)q * 384 + c * 2];
        float rx = fminf(fmaxf(ref[q * 2 + 0], 0.f), 1.f);
        float ry = fminf(fmaxf(ref[q * 2 + 1], 0.f), 1.f);
        const float eps = 1e-5f;
        const float isx = logf(fmaxf(rx, eps) / fmaxf(1.f - rx, eps));
        const float isy = logf(fmaxf(ry, eps) / fmaxf(1.f - ry, eps));
        const float locx = 1.f / (1.f + expf(-(isx + off.x)));
        const float locy = 1.f / (1.f + expf(-(isy + off.y)));
        const int Wl = HMAX >> l, Hl = HMAX >> l;
        const float x = locx * (float)Wl - 0.5f;
        const float y = locy * (float)Hl - 0.5f;
        const float x0f = floorf(x), y0f = floorf(y);
        const float wx1 = x - x0f, wx0 = 1.f - wx1;
        const float wy1 = y - y0f, wy0 = 1.f - wy1;
        const int x0 = (int)x0f, y0 = (int)y0f;
        const int lo = (l == 0) ? 0 : (l == 1) ? 16384 : (l == 2) ? 20480 : 21504;
        const int base = b * NV_PER_B + lo;
        const int   xs[2] = {x0, x0 + 1};
        const int   ys[2] = {y0, y0 + 1};
        const float wxs[2] = {wx0, wx1};
        const float wys[2] = {wy0, wy1};
        #pragma unroll
        for (int cy = 0; cy < 2; ++cy)
            #pragma unroll
            for (int cx = 0; cx < 2; ++cx) {
                const int xi = xs[cx], yi = ys[cy];
                const bool valid = (xi >= 0) & (xi < Wl) & (yi >= 0) & (yi < Hl);
                const int idx = cy * 2 + cx;
                s_rw[c][idx].x = valid ? (base + yi * Wl + xi) : 0;
                s_rw[c][idx].y = __float_as_int(valid ? (wys[cy] * wxs[cx]) : 0.f);
            }
        s_logit[lp][c & 7] = qbuf[(size_t)q * 384 + 256 + c];
    }
    __syncthreads();

    if (tid < 8) {
        const int h = tid;
        float m = -INFINITY;
        #pragma unroll
        for (int j = 0; j < 16; ++j) m = fmaxf(m, s_logit[j][h]);
        float s = 0.f;
        #pragma unroll
        for (int j = 0; j < 16; ++j) s += expf(s_logit[j][h] - m);
        const float inv = 1.f / s;
        #pragma unroll
        for (int j = 0; j < 16; ++j)
            s_aw[j][h] = expf(s_logit[j][h] - m) * inv;
    }
    __syncthreads();

    #pragma unroll
    for (int t2 = tid; t2 < 512; t2 += 256) {
        const int c = t2 >> 2, j = t2 & 3;
        const float aw = s_aw[c >> 3][c & 7];
        s_rw[c][j].y = __float_as_int(__int_as_float(s_rw[c][j].y) * aw);
    }
    __syncthreads();

    const int h  = tid >> 5;
    const int l5 = tid & 31;
    const int ds = l5 & 3;
    const int rt = l5 >> 2;
    const int j  = rt & 3;
    const int rtH = rt >> 2;

    float a0 = 0.f, a1 = 0.f, a2 = 0.f, a3 = 0.f;
    float a4 = 0.f, a5 = 0.f, a6 = 0.f, a7 = 0.f;
    #pragma unroll
    for (int it = 0; it < 8; ++it) {
        const int lp = 2 * it + rtH;
        const int c = lp * 8 + h;
        const int2 rw = s_rw[c][j];
        const float w = __int_as_float(rw.y);
        const uint4 u = *(const uint4*)&vproj[(size_t)rw.x * 256 + h * 32 + ds * 8];
        a0 = fmaf(w, __builtin_bit_cast(float, u.x << 16), a0);
        a1 = fmaf(w, __builtin_bit_cast(float, u.x & 0xFFFF0000u), a1);
        a2 = fmaf(w, __builtin_bit_cast(float, u.y << 16), a2);
        a3 = fmaf(w, __builtin_bit_cast(float, u.y & 0xFFFF0000u), a3);
        a4 = fmaf(w, __builtin_bit_cast(float, u.z << 16), a4);
        a5 = fmaf(w, __builtin_bit_cast(float, u.z & 0xFFFF0000u), a5);
        a6 = fmaf(w, __builtin_bit_cast(float, u.w << 16), a6);
        a7 = fmaf(w, __builtin_bit_cast(float, u.w & 0xFFFF0000u), a7);
    }
    #pragma unroll
    for (int m = 4; m <= 16; m <<= 1) {
        a0 += __shfl_xor(a0, m); a1 += __shfl_xor(a1, m);
        a2 += __shfl_xor(a2, m); a3 += __shfl_xor(a3, m);
        a4 += __shfl_xor(a4, m); a5 += __shfl_xor(a5, m);
        a6 += __shfl_xor(a6, m); a7 += __shfl_xor(a7, m);
    }
    if (rt == 0) {
        float* dst = &mid[(size_t)q * 256 + h * 32 + ds * 8];
        float4 o0 = {a0, a1, a2, a3};
        float4 o1 = {a4, a5, a6, a7};
        *(float4*)dst = o0;
        *(float4*)(dst + 4) = o1;
    }
}

// ---------------------------------------------------------------------------
extern "C" void kernel_launch(void* const* d_in, const int* in_sizes, int n_in,
                              void* d_out, int out_size, void* d_ws, size_t ws_size,
                              hipStream_t stream)
{
    const float* query  = (const float*)d_in[0];
    const float* ref    = (const float*)d_in[1];
    const float* values = (const float*)d_in[2];
    const float* W_so   = (const float*)d_in[3];
    const float* b_so   = (const float*)d_in[4];
    const float* W_aw   = (const float*)d_in[5];
    const float* b_aw   = (const float*)d_in[6];
    const float* W_v    = (const float*)d_in[7];
    const float* b_v    = (const float*)d_in[8];
    const float* W_o    = (const float*)d_in[9];
    const float* b_o    = (const float*)d_in[10];
    float* out = (float*)d_out;

    ushort* vproj = (ushort*)d_ws;                     // [43520][256] bf16
    float* qbuf  = (float*)d_ws + ((size_t)MROWS * 256 * 2) / 4;  // [8192][384] f32
    float* mid   = qbuf + (size_t)QTOT * 384;          // [8192][256] f32

    dim3 blk(256);
    // 1+2) grouped direct GEMMs: vproj (1360 blocks) ++ query proj (384)
    fused_g12<<<dim3(G1_BLKS + G2_BLKS), blk, 0, stream>>>(
        values, W_v, b_v, query, W_so, W_aw, b_so, b_aw, vproj, qbuf);
    // 3) deformable sampling + softmax-weighted head accumulation
    sample1<<<dim3(QTOT), blk, 0, stream>>>(vproj, qbuf, ref, mid);
    // 4) output projection
    gemm_o<<<dim3(64, 4), blk, 0, stream>>>(mid, W_o, b_o, out);
}